// Round 3
// baseline (113.738 us; speedup 1.0000x reference)
//
#include <hip/hip_runtime.h>
#include <stdint.h>

// DSN few-shot classifier, MI355X.
// out[q][w] = log_softmax_w( ||P9_w q||^2 ),  query-norm cancels in softmax.
// P9 = P_colspace - u_min u_min^T, so s_w = ||B^T q||^2 - (u_min . q)^2 with
// B = M L^{-T} (G = L L^T Cholesky) an exact ONB of colspace(M).
//
// ws layout:
//   [0,      4000)  G    : 5*10*10 double (Gram matrices, full storage)
//   [8192, 172032)  Upad : 80*1024 bf16   (way w -> rows 16w..16w+10; rest zero)

typedef __attribute__((ext_vector_type(4))) float f32x4;
typedef __attribute__((ext_vector_type(8))) short s16x8;

#define WS_G_OFF    0
#define WS_U_OFF    8192

__device__ __forceinline__ unsigned short f2bf(float f) {
  unsigned int u = __float_as_uint(f);
  u += 0x7FFFu + ((u >> 16) & 1u);   // round-to-nearest-even
  return (unsigned short)(u >> 16);
}

__device__ __forceinline__ constexpr int PU(int i, int j) {  // upper packed, i<=j
  return 10 * i - i * (i - 1) / 2 + (j - i);
}
__device__ __forceinline__ constexpr int PL(int i, int j) {  // strict lower, i>j
  return i * (i - 1) / 2 + j;
}
__device__ __forceinline__ constexpr int CI(int i, int j) {  // lower incl diag, i>=j
  return i * (i + 1) / 2 + j;
}

// int64 vs int32 one-hot labels detection (validated R0).
__device__ __forceinline__ bool labels_int64(const int* L) {
  int cnt = 0; bool oddz = true;
  #pragma unroll
  for (int t = 0; t < 20; ++t) {
    int v = L[t];
    if (t & 1) { if (v) oddz = false; }
    else       { if (v) cnt++; }
  }
  return oddz && (cnt == 2);
}

__device__ __forceinline__ int cls_of(const int* L, bool is64, int i) {
  int best = -0x7fffffff, c = 0;
  #pragma unroll
  for (int j = 0; j < 5; ++j) {
    int v = is64 ? L[i * 10 + 2 * j] : L[i * 5 + j];
    if (v > best) { best = v; c = j; }
  }
  return c;
}

// ---------------- Kernel A1: Gram matrices, one wave per (w,a,b) pair -------
__global__ void dsn_gram(const float* __restrict__ support,
                         const int* __restrict__ labels,
                         double* __restrict__ G) {
  int wid  = blockIdx.x * 4 + (threadIdx.x >> 6);
  int lane = threadIdx.x & 63;
  if (wid >= 275) return;               // 5 ways * 55 upper-tri pairs
  int w = wid / 55, p = wid % 55;
  int a = 0;
  while (p >= 10 - a) { p -= 10 - a; a++; }
  int b = a + p;                        // a <= b

  bool is64 = labels_int64(labels);
  int myc = (lane < 50) ? cls_of(labels, is64, lane) : -1;
  unsigned long long mask = __ballot(lane < 50 && myc == w);

  unsigned long long m = mask;
  for (int i = 0; i < a; ++i) m &= m - 1;
  int ia = __ffsll((unsigned long long)m) - 1;
  m = mask;
  for (int i = 0; i < b; ++i) m &= m - 1;
  int ib = __ffsll((unsigned long long)m) - 1;

  const float* A = support + ia * 1024;
  const float* B = support + ib * 1024;
  double acc = 0.0;
  #pragma unroll
  for (int i = 0; i < 16; ++i) {
    int d = lane + 64 * i;
    acc += (double)A[d] * (double)B[d];
  }
  #pragma unroll
  for (int off = 32; off > 0; off >>= 1) acc += __shfl_xor(acc, off);
  if (lane == 0) {
    G[(w * 10 + a) * 10 + b] = acc;
    G[(w * 10 + b) * 10 + a] = acc;
  }
}

// ---------------- register-resident 10x10 fp32 linear algebra ---------------
// LDL^T of (G - sigma I); returns count of negative pivots (Sylvester inertia).
__device__ __forceinline__ int ldl10f(const float (&g)[55], float sigma,
                                      float (&Lw)[45], float (&d)[10]) {
  int neg = 0;
  #pragma unroll
  for (int j = 0; j < 10; ++j) {
    float s = g[PU(j, j)] - sigma;
    #pragma unroll
    for (int k = 0; k < j; ++k) s -= Lw[PL(j, k)] * Lw[PL(j, k)] * d[k];
    if (fabsf(s) < 1e-4f) s = -1e-4f;   // inertia guard (never hits at final sigma)
    d[j] = s;
    if (s < 0.f) neg++;
    float inv = 1.f / s;
    #pragma unroll
    for (int i = j + 1; i < 10; ++i) {
      float t = g[PU(j, i)];
      #pragma unroll
      for (int k = 0; k < j; ++k) t -= Lw[PL(i, k)] * Lw[PL(j, k)] * d[k];
      Lw[PL(i, j)] = t * inv;
    }
  }
  return neg;
}

// solve (L D L^T) x = x in place (L unit strict-lower packed).
__device__ __forceinline__ void ldlsolve10f(const float (&Lw)[45],
                                            const float (&d)[10],
                                            float (&x)[10]) {
  #pragma unroll
  for (int i = 1; i < 10; ++i) {
    #pragma unroll
    for (int j = 0; j < i; ++j) x[i] -= Lw[PL(i, j)] * x[j];
  }
  #pragma unroll
  for (int i = 0; i < 10; ++i) x[i] *= (1.f / d[i]);
  #pragma unroll
  for (int i = 8; i >= 0; --i) {
    #pragma unroll
    for (int j = i + 1; j < 10; ++j) x[i] -= Lw[PL(j, i)] * x[j];
  }
}

// -------- Kernel A2: fused subspace prep (1 block), writes Upad bf16 --------
// Wave 0, 12 lanes/way: parallel-shift inertia slicing -> lambda_min bracket,
// inverse iteration for v_min, redundant Cholesky + 1 back-sub column/lane.
// Then all 256 threads materialize Upad (80 x 1024 bf16).
__global__ __launch_bounds__(256, 1) void dsn_prep(const float* __restrict__ support,
                                                   const int* __restrict__ labels,
                                                   const double* __restrict__ G,
                                                   unsigned short* __restrict__ U) {
  __shared__ int cls[50];
  __shared__ int idxs[5][10];
  __shared__ float Wsm[5][11][10];
  int t = threadIdx.x;
  bool is64 = labels_int64(labels);
  if (t < 50) cls[t] = cls_of(labels, is64, t);
  __syncthreads();
  if (t < 5) {
    int s = 0;
    for (int i = 0; i < 50; ++i)
      if (cls[i] == t) { idxs[t][s] = i; s++; }
  }
  __syncthreads();

  if (t < 60) {
    int w = t / 12, s5 = t % 12;
    float gg[55];
    #pragma unroll
    for (int i = 0; i < 10; ++i)
      #pragma unroll
      for (int j = i; j < 10; ++j)
        gg[PU(i, j)] = (float)G[(w * 10 + i) * 10 + j];

    // Gershgorin bracket for lambda_min: [lo, hi]
    float lo = 1e30f, hi = 1e30f;
    #pragma unroll
    for (int i = 0; i < 10; ++i) {
      float r = 0.f, di = gg[PU(i, i)];
      #pragma unroll
      for (int j = 0; j < 10; ++j) {
        if (j == i) continue;
        float v = (j < i) ? gg[PU(j, i)] : gg[PU(i, j)];
        r += fabsf(v);
      }
      lo = fminf(lo, di - r);
      hi = fminf(hi, di);
    }
    lo = fmaxf(lo, 0.f);
    hi = hi + 1.f;

    float Lw[45], dp[10];
    // two rounds of 12-point parallel inertia slicing: width /= ~169
    #pragma unroll 1
    for (int round = 0; round < 2; ++round) {
      float shift = lo + (hi - lo) * (float)(s5 + 1) * (1.f / 13.f);
      int neg = ldl10f(gg, shift, Lw, dp);
      float nlo = lo, nhi = hi;
      #pragma unroll 1
      for (int u = 0; u < 12; ++u) {
        float sh = __shfl(shift, w * 12 + u);
        int   ng = __shfl(neg,   w * 12 + u);
        if (ng == 0) nlo = fmaxf(nlo, sh);
        else         nhi = fminf(nhi, sh);
      }
      lo = nlo; hi = nhi;
    }
    float sigma = lo - (hi - lo) - 0.5f;   // strictly below lambda_min, cond-safe

    // inverse iteration for v_min (all 12 lanes redundant, zero comms)
    ldl10f(gg, sigma, Lw, dp);
    float x[10];
    #pragma unroll
    for (int i = 0; i < 10; ++i) x[i] = 1.f;
    #pragma unroll 1
    for (int itr = 0; itr < 4; ++itr) {
      ldlsolve10f(Lw, dp, x);
      float mx = 0.f;
      #pragma unroll
      for (int i = 0; i < 10; ++i) mx = fmaxf(mx, fabsf(x[i]));
      float rm = 1.f / mx;
      #pragma unroll
      for (int i = 0; i < 10; ++i) x[i] *= rm;
    }
    // row 10: v / ||M v||,  ||M v||^2 = v^T G v
    float denom = 0.f;
    #pragma unroll
    for (int i = 0; i < 10; ++i) {
      float gv = 0.f;
      #pragma unroll
      for (int j = 0; j < 10; ++j) {
        float v = (j < i) ? gg[PU(j, i)] : gg[PU(i, j)];
        gv += v * x[j];
      }
      denom += x[i] * gv;
    }
    float sc = 1.f / sqrtf(denom);
    if (s5 == 0) {
      #pragma unroll
      for (int j = 0; j < 10; ++j) Wsm[w][10][j] = x[j] * sc;
    }

    // Cholesky G = Lc Lc^T (redundant in all 12 lanes; disjoint live range)
    float Lc[55];
    #pragma unroll
    for (int j = 0; j < 10; ++j) {
      float s = gg[PU(j, j)];
      #pragma unroll
      for (int k = 0; k < j; ++k) s -= Lc[CI(j, k)] * Lc[CI(j, k)];
      float dj = sqrtf(s);
      Lc[CI(j, j)] = dj;
      float inv = 1.f / dj;
      #pragma unroll
      for (int i = j + 1; i < 10; ++i) {
        float tt = gg[PU(j, i)];
        #pragma unroll
        for (int k = 0; k < j; ++k) tt -= Lc[CI(i, k)] * Lc[CI(j, k)];
        Lc[CI(i, j)] = tt * inv;
      }
    }
    // lane s5<10 back-substitutes column s5 of L^{-T}: solve L^T c = e_{s5}
    if (s5 < 10) {
      float c[10];
      #pragma unroll
      for (int q2 = 9; q2 >= 0; --q2) {
        float tt = (q2 == s5) ? 1.f : 0.f;
        #pragma unroll
        for (int u2 = q2 + 1; u2 < 10; ++u2) tt -= Lc[CI(u2, q2)] * c[u2];
        c[q2] = tt / Lc[CI(q2, q2)];
      }
      #pragma unroll
      for (int j = 0; j < 10; ++j) Wsm[w][s5][j] = c[j];
    }
  }
  __syncthreads();

  // basis: Upad rows 0..79 (row 16w+kk: kk<11 -> B/u_min, else zero)
  #pragma unroll 1
  for (int r = 0; r < 80; ++r) {
    int w = r >> 4, kk = r & 15;
    unsigned short* Urow = U + r * 1024;
    if (kk >= 11) {
      for (int d0 = t; d0 < 1024; d0 += 256) Urow[d0] = 0;
    } else {
      for (int d0 = t; d0 < 1024; d0 += 256) {
        float sum = 0.f;
        #pragma unroll
        for (int s2 = 0; s2 < 10; ++s2)
          sum += support[idxs[w][s2] * 1024 + d0] * Wsm[w][kk][s2];
        Urow[d0] = f2bf(sum);
      }
    }
  }
}

// ---------------- Kernel B: main — MFMA coeffs + log_softmax ---------------
// 16 queries per wave. A = Upad (5 row-tiles, one per way), B = Q^T fragment.
// D[row=channel][col=query]: col = lane&15, row = (lane>>4)*4 + reg  (m89).
// Row 10 (u_min) lives at lane-group 2, reg 2 -> its square is SUBTRACTED.
__global__ __launch_bounds__(256) void dsn_main(const float* __restrict__ query,
                                                const unsigned short* __restrict__ U,
                                                float* __restrict__ out) {
  int wid  = blockIdx.x * 4 + (threadIdx.x >> 6);
  int lane = threadIdx.x & 63;
  int q0   = wid * 16;
  int qrow = lane & 15;
  int kbase = (lane >> 4) * 8;

  const float* qp = query + (size_t)(q0 + qrow) * 1024 + kbase;
  const unsigned short* up = U + qrow * 1024 + kbase;

  f32x4 acc[5];
  #pragma unroll
  for (int w = 0; w < 5; ++w) acc[w] = (f32x4){0.f, 0.f, 0.f, 0.f};

  #pragma unroll 4
  for (int kt = 0; kt < 32; ++kt) {
    const float* qk = qp + kt * 32;
    f32x4 lo = *(const f32x4*)qk;
    f32x4 hi = *(const f32x4*)(qk + 4);
    s16x8 bf;
    bf[0] = (short)f2bf(lo[0]); bf[1] = (short)f2bf(lo[1]);
    bf[2] = (short)f2bf(lo[2]); bf[3] = (short)f2bf(lo[3]);
    bf[4] = (short)f2bf(hi[0]); bf[5] = (short)f2bf(hi[1]);
    bf[6] = (short)f2bf(hi[2]); bf[7] = (short)f2bf(hi[3]);
    const unsigned short* uk = up + kt * 32;
    #pragma unroll
    for (int w = 0; w < 5; ++w) {
      s16x8 av = *(const s16x8*)(uk + w * 16384);   // row w*16 + qrow
      acc[w] = __builtin_amdgcn_mfma_f32_16x16x32_bf16(av, bf, acc[w], 0, 0, 0);
    }
  }

  // s_w = sum_{rows 0..9} c^2 - c_10^2 (rows 11..15 zero-padded)
  float sgn2 = ((lane >> 4) == 2) ? -1.f : 1.f;   // reg 2 of group 2 = row 10
  float sv[5];
  #pragma unroll
  for (int w = 0; w < 5; ++w) {
    float tcc = acc[w][0] * acc[w][0] + acc[w][1] * acc[w][1] +
                sgn2 * acc[w][2] * acc[w][2] + acc[w][3] * acc[w][3];
    tcc += __shfl_xor(tcc, 16);
    tcc += __shfl_xor(tcc, 32);
    sv[w] = tcc;
  }
  float mx = fmaxf(fmaxf(fmaxf(sv[0], sv[1]), fmaxf(sv[2], sv[3])), sv[4]);
  float sum = 0.f;
  #pragma unroll
  for (int w = 0; w < 5; ++w) sum += expf(sv[w] - mx);
  float lse = mx + logf(sum);
  if (lane < 16) {
    float* o = out + (size_t)(q0 + lane) * 5;
    #pragma unroll
    for (int w = 0; w < 5; ++w) o[w] = sv[w] - lse;
  }
}

extern "C" void kernel_launch(void* const* d_in, const int* in_sizes, int n_in,
                              void* d_out, int out_size, void* d_ws, size_t ws_size,
                              hipStream_t stream) {
  const float* support = (const float*)d_in[0];
  const int*   labels  = (const int*)d_in[1];
  const float* query   = (const float*)d_in[2];
  float* out = (float*)d_out;
  char* ws = (char*)d_ws;

  double*         G = (double*)(ws + WS_G_OFF);
  unsigned short* U = (unsigned short*)(ws + WS_U_OFF);

  int nq = in_sizes[2] / 1024;          // 16384
  int nwaves = nq / 16;                 // 1024
  int nblocks = (nwaves + 3) / 4;       // 256

  hipLaunchKernelGGL(dsn_gram, dim3(69), dim3(256), 0, stream, support, labels, G);
  hipLaunchKernelGGL(dsn_prep, dim3(1),  dim3(256), 0, stream, support, labels, G, U);
  hipLaunchKernelGGL(dsn_main, dim3(nblocks), dim3(256), 0, stream, query, U, out);
}

// Round 4
// 64.226 us; speedup vs baseline: 1.7709x; 1.7709x over previous
//
#include <hip/hip_runtime.h>
#include <stdint.h>

// DSN few-shot classifier, MI355X.
// out[q][w] = log_softmax_w( ||P9_w q||^2 ),  query-norm cancels in softmax.
// P9 = P_colspace - u_min u_min^T, so s_w = ||B^T q||^2 - (u_min . q)^2 with
// B = M L^{-T} (G = L L^T Cholesky) an exact ONB of colspace(M).
//
// ws layout:
//   [0,      4000)  G    : 5*10*10 double (Gram matrices, full storage)
//   [4096,   6296)  W    : 5*11*10 float  (rows 0..9: L^{-T} cols; row 10: v_min/|Mv|)
//   [6400,   6600)  idx  : 5*10 int       (support indices per way)
//   [8192, 172032)  Upad : 80*1024 bf16   (way w -> rows 16w..16w+10; rest zero)

typedef __attribute__((ext_vector_type(4))) float f32x4;
typedef __attribute__((ext_vector_type(8))) short s16x8;

#define WS_G_OFF    0
#define WS_W_OFF    4096
#define WS_IDX_OFF  6400
#define WS_U_OFF    8192

__device__ __forceinline__ unsigned short f2bf(float f) {
  unsigned int u = __float_as_uint(f);
  u += 0x7FFFu + ((u >> 16) & 1u);   // round-to-nearest-even
  return (unsigned short)(u >> 16);
}

__device__ __forceinline__ constexpr int PU(int i, int j) {  // upper packed, i<=j
  return 10 * i - i * (i - 1) / 2 + (j - i);
}
__device__ __forceinline__ constexpr int PL(int i, int j) {  // strict lower, i>j
  return i * (i - 1) / 2 + j;
}
__device__ __forceinline__ constexpr int CI(int i, int j) {  // lower incl diag, i>=j
  return i * (i + 1) / 2 + j;
}

// int64 vs int32 one-hot labels detection (validated R0).
__device__ __forceinline__ bool labels_int64(const int* L) {
  int cnt = 0; bool oddz = true;
  #pragma unroll
  for (int t = 0; t < 20; ++t) {
    int v = L[t];
    if (t & 1) { if (v) oddz = false; }
    else       { if (v) cnt++; }
  }
  return oddz && (cnt == 2);
}

__device__ __forceinline__ int cls_of(const int* L, bool is64, int i) {
  int best = -0x7fffffff, c = 0;
  #pragma unroll
  for (int j = 0; j < 5; ++j) {
    int v = is64 ? L[i * 10 + 2 * j] : L[i * 5 + j];
    if (v > best) { best = v; c = j; }
  }
  return c;
}

// ---------------- Kernel A1: Gram matrices, one wave per (w,a,b) pair -------
__global__ void dsn_gram(const float* __restrict__ support,
                         const int* __restrict__ labels,
                         double* __restrict__ G) {
  int wid  = blockIdx.x * 4 + (threadIdx.x >> 6);
  int lane = threadIdx.x & 63;
  if (wid >= 275) return;               // 5 ways * 55 upper-tri pairs
  int w = wid / 55, p = wid % 55;
  int a = 0;
  while (p >= 10 - a) { p -= 10 - a; a++; }
  int b = a + p;                        // a <= b

  bool is64 = labels_int64(labels);
  int myc = (lane < 50) ? cls_of(labels, is64, lane) : -1;
  unsigned long long mask = __ballot(lane < 50 && myc == w);

  unsigned long long m = mask;
  for (int i = 0; i < a; ++i) m &= m - 1;
  int ia = __ffsll((unsigned long long)m) - 1;
  m = mask;
  for (int i = 0; i < b; ++i) m &= m - 1;
  int ib = __ffsll((unsigned long long)m) - 1;

  const float* A = support + ia * 1024;
  const float* B = support + ib * 1024;
  double acc = 0.0;
  #pragma unroll
  for (int i = 0; i < 16; ++i) {
    int d = lane + 64 * i;
    acc += (double)A[d] * (double)B[d];
  }
  #pragma unroll
  for (int off = 32; off > 0; off >>= 1) acc += __shfl_xor(acc, off);
  if (lane == 0) {
    G[(w * 10 + a) * 10 + b] = acc;
    G[(w * 10 + b) * 10 + a] = acc;
  }
}

// ------------- fp32 10x10 LA; G lives in LDS (broadcast reads) -------------
// LDL^T of (G - sigma I); returns count of negative pivots (Sylvester inertia).
// Only Lw[45]+d[10] live in registers -> no spills at any VGPR budget >=~80.
__device__ __forceinline__ int ldl10f(const float* g, float sigma,
                                      float (&Lw)[45], float (&d)[10]) {
  int neg = 0;
  #pragma unroll
  for (int j = 0; j < 10; ++j) {
    float s = g[PU(j, j)] - sigma;
    #pragma unroll
    for (int k = 0; k < j; ++k) s -= Lw[PL(j, k)] * Lw[PL(j, k)] * d[k];
    if (fabsf(s) < 1e-4f) s = -1e-4f;   // inertia guard (never hits at final sigma)
    d[j] = s;
    if (s < 0.f) neg++;
    float inv = 1.f / s;
    #pragma unroll
    for (int i = j + 1; i < 10; ++i) {
      float t = g[PU(j, i)];
      #pragma unroll
      for (int k = 0; k < j; ++k) t -= Lw[PL(i, k)] * Lw[PL(j, k)] * d[k];
      Lw[PL(i, j)] = t * inv;
    }
  }
  return neg;
}

// solve (L D L^T) x = x in place (L unit strict-lower packed).
__device__ __forceinline__ void ldlsolve10f(const float (&Lw)[45],
                                            const float (&d)[10],
                                            float (&x)[10]) {
  #pragma unroll
  for (int i = 1; i < 10; ++i) {
    #pragma unroll
    for (int j = 0; j < i; ++j) x[i] -= Lw[PL(i, j)] * x[j];
  }
  #pragma unroll
  for (int i = 0; i < 10; ++i) x[i] *= (1.f / d[i]);
  #pragma unroll
  for (int i = 8; i >= 0; --i) {
    #pragma unroll
    for (int j = i + 1; j < 10; ++j) x[i] -= Lw[PL(j, i)] * x[j];
  }
}

// -------- Kernel A2: subspace solve, 1 block x 64 threads, LDS-backed G -----
// 12 lanes/way: parallel-shift inertia slicing -> lambda_min bracket, inverse
// iteration for v_min; redundant Cholesky, 1 back-sub column per lane.
__global__ __launch_bounds__(64, 1) void dsn_eig(const int* __restrict__ labels,
                                                 const double* __restrict__ G,
                                                 float* __restrict__ W,
                                                 int* __restrict__ idx) {
  __shared__ int cls[50];
  __shared__ float gsm[5][56];          // packed-upper Gram, fp32
  int t = threadIdx.x;
  bool is64 = labels_int64(labels);
  if (t < 50) cls[t] = cls_of(labels, is64, t);
  for (int i = t; i < 5 * 55; i += 64) {
    int w = i / 55, p = i % 55;
    int r = 0, pp = p;
    while (pp >= 10 - r) { pp -= 10 - r; r++; }
    int c = r + pp;
    gsm[w][p] = (float)G[(w * 10 + r) * 10 + c];
  }
  __syncthreads();
  if (t < 5) {
    int s = 0;
    for (int i = 0; i < 50; ++i)
      if (cls[i] == t) { idx[t * 10 + s] = i; s++; }
  }
  if (t >= 60) return;
  int w = t / 12, s5 = t % 12;
  const float* g = gsm[w];

  // Gershgorin bracket for lambda_min: [lo, hi]
  float lo = 1e30f, hi = 1e30f;
  #pragma unroll
  for (int i = 0; i < 10; ++i) {
    float r = 0.f, di = g[PU(i, i)];
    #pragma unroll
    for (int j = 0; j < 10; ++j) {
      if (j == i) continue;
      float v = (j < i) ? g[PU(j, i)] : g[PU(i, j)];
      r += fabsf(v);
    }
    lo = fminf(lo, di - r);
    hi = fminf(hi, di);
  }
  lo = fmaxf(lo, 0.f);
  hi = hi + 1.f;

  float Lw[45], dp[10];
  // two rounds of 12-point parallel inertia slicing: width /= ~169
  #pragma unroll 1
  for (int round = 0; round < 2; ++round) {
    float shift = lo + (hi - lo) * (float)(s5 + 1) * (1.f / 13.f);
    int neg = ldl10f(g, shift, Lw, dp);
    float nlo = lo, nhi = hi;
    #pragma unroll 1
    for (int u = 0; u < 12; ++u) {
      float sh = __shfl(shift, w * 12 + u);
      int   ng = __shfl(neg,   w * 12 + u);
      if (ng == 0) nlo = fmaxf(nlo, sh);
      else         nhi = fminf(nhi, sh);
    }
    lo = nlo; hi = nhi;
  }
  float sigma = lo - (hi - lo) - 0.5f;   // strictly below lambda_min, cond-safe

  // inverse iteration for v_min (all 12 lanes redundant, zero comms)
  ldl10f(g, sigma, Lw, dp);
  float x[10];
  #pragma unroll
  for (int i = 0; i < 10; ++i) x[i] = 1.f;
  #pragma unroll 1
  for (int itr = 0; itr < 4; ++itr) {
    ldlsolve10f(Lw, dp, x);
    float mx = 0.f;
    #pragma unroll
    for (int i = 0; i < 10; ++i) mx = fmaxf(mx, fabsf(x[i]));
    float rm = 1.f / mx;
    #pragma unroll
    for (int i = 0; i < 10; ++i) x[i] *= rm;
  }
  // row 10: v / ||M v||,  ||M v||^2 = v^T G v
  float denom = 0.f;
  #pragma unroll
  for (int i = 0; i < 10; ++i) {
    float gv = 0.f;
    #pragma unroll
    for (int j = 0; j < 10; ++j) {
      float v = (j < i) ? g[PU(j, i)] : g[PU(i, j)];
      gv += v * x[j];
    }
    denom += x[i] * gv;
  }
  float sc = 1.f / sqrtf(denom);
  if (s5 == 0) {
    #pragma unroll
    for (int j = 0; j < 10; ++j) W[(w * 11 + 10) * 10 + j] = x[j] * sc;
  }

  // Cholesky G = Lc Lc^T (redundant in all 12 lanes; Lw dead by now)
  float Lc[55];
  #pragma unroll
  for (int j = 0; j < 10; ++j) {
    float s = g[PU(j, j)];
    #pragma unroll
    for (int k = 0; k < j; ++k) s -= Lc[CI(j, k)] * Lc[CI(j, k)];
    float dj = sqrtf(s);
    Lc[CI(j, j)] = dj;
    float inv = 1.f / dj;
    #pragma unroll
    for (int i = j + 1; i < 10; ++i) {
      float tt = g[PU(j, i)];
      #pragma unroll
      for (int k = 0; k < j; ++k) tt -= Lc[CI(i, k)] * Lc[CI(j, k)];
      Lc[CI(i, j)] = tt * inv;
    }
  }
  // lane s5<10 back-substitutes column s5 of L^{-T}: solve L^T c = e_{s5}
  if (s5 < 10) {
    float c[10];
    #pragma unroll
    for (int q2 = 9; q2 >= 0; --q2) {
      float tt = (q2 == s5) ? 1.f : 0.f;
      #pragma unroll
      for (int u2 = q2 + 1; u2 < 10; ++u2) tt -= Lc[CI(u2, q2)] * c[u2];
      c[q2] = tt / Lc[CI(q2, q2)];
    }
    #pragma unroll
    for (int j = 0; j < 10; ++j) W[(w * 11 + s5) * 10 + j] = c[j];
  }
}

// ---------------- Kernel A3: materialize Upad (80 x 1024 bf16) -------------
__global__ void dsn_basis(const float* __restrict__ support,
                          const float* __restrict__ W,
                          const int* __restrict__ idx,
                          unsigned short* __restrict__ U) {
  int r = blockIdx.x;              // 0..79
  int w = r >> 4, kk = r & 15;
  unsigned short* Urow = U + r * 1024;
  if (kk >= 11) {
    for (int d = threadIdx.x; d < 1024; d += 256) Urow[d] = 0;
    return;
  }
  float wv[10]; int id[10];
  #pragma unroll
  for (int s = 0; s < 10; ++s) {
    wv[s] = W[(w * 11 + kk) * 10 + s];
    id[s] = idx[w * 10 + s];
  }
  for (int d = threadIdx.x; d < 1024; d += 256) {
    float sum = 0.f;
    #pragma unroll
    for (int s = 0; s < 10; ++s) sum += support[id[s] * 1024 + d] * wv[s];
    Urow[d] = f2bf(sum);
  }
}

// ---------------- Kernel B: main — MFMA coeffs + log_softmax ---------------
// 16 queries per wave. A = Upad (5 row-tiles, one per way), B = Q^T fragment.
// D[row=channel][col=query]: col = lane&15, row = (lane>>4)*4 + reg  (m89).
// Row 10 (u_min) lives at lane-group 2, reg 2 -> its square is SUBTRACTED.
__global__ __launch_bounds__(256) void dsn_main(const float* __restrict__ query,
                                                const unsigned short* __restrict__ U,
                                                float* __restrict__ out) {
  int wid  = blockIdx.x * 4 + (threadIdx.x >> 6);
  int lane = threadIdx.x & 63;
  int q0   = wid * 16;
  int qrow = lane & 15;
  int kbase = (lane >> 4) * 8;

  const float* qp = query + (size_t)(q0 + qrow) * 1024 + kbase;
  const unsigned short* up = U + qrow * 1024 + kbase;

  f32x4 acc[5];
  #pragma unroll
  for (int w = 0; w < 5; ++w) acc[w] = (f32x4){0.f, 0.f, 0.f, 0.f};

  #pragma unroll 4
  for (int kt = 0; kt < 32; ++kt) {
    const float* qk = qp + kt * 32;
    f32x4 lo = *(const f32x4*)qk;
    f32x4 hi = *(const f32x4*)(qk + 4);
    s16x8 bf;
    bf[0] = (short)f2bf(lo[0]); bf[1] = (short)f2bf(lo[1]);
    bf[2] = (short)f2bf(lo[2]); bf[3] = (short)f2bf(lo[3]);
    bf[4] = (short)f2bf(hi[0]); bf[5] = (short)f2bf(hi[1]);
    bf[6] = (short)f2bf(hi[2]); bf[7] = (short)f2bf(hi[3]);
    const unsigned short* uk = up + kt * 32;
    #pragma unroll
    for (int w = 0; w < 5; ++w) {
      s16x8 av = *(const s16x8*)(uk + w * 16384);   // row w*16 + qrow
      acc[w] = __builtin_amdgcn_mfma_f32_16x16x32_bf16(av, bf, acc[w], 0, 0, 0);
    }
  }

  // s_w = sum_{rows 0..9} c^2 - c_10^2 (rows 11..15 zero-padded)
  float sgn2 = ((lane >> 4) == 2) ? -1.f : 1.f;   // reg 2 of group 2 = row 10
  float sv[5];
  #pragma unroll
  for (int w = 0; w < 5; ++w) {
    float tcc = acc[w][0] * acc[w][0] + acc[w][1] * acc[w][1] +
                sgn2 * acc[w][2] * acc[w][2] + acc[w][3] * acc[w][3];
    tcc += __shfl_xor(tcc, 16);
    tcc += __shfl_xor(tcc, 32);
    sv[w] = tcc;
  }
  float mx = fmaxf(fmaxf(fmaxf(sv[0], sv[1]), fmaxf(sv[2], sv[3])), sv[4]);
  float sum = 0.f;
  #pragma unroll
  for (int w = 0; w < 5; ++w) sum += expf(sv[w] - mx);
  float lse = mx + logf(sum);
  if (lane < 16) {
    float* o = out + (size_t)(q0 + lane) * 5;
    #pragma unroll
    for (int w = 0; w < 5; ++w) o[w] = sv[w] - lse;
  }
}

extern "C" void kernel_launch(void* const* d_in, const int* in_sizes, int n_in,
                              void* d_out, int out_size, void* d_ws, size_t ws_size,
                              hipStream_t stream) {
  const float* support = (const float*)d_in[0];
  const int*   labels  = (const int*)d_in[1];
  const float* query   = (const float*)d_in[2];
  float* out = (float*)d_out;
  char* ws = (char*)d_ws;

  double*         G   = (double*)(ws + WS_G_OFF);
  float*          W   = (float*)(ws + WS_W_OFF);
  int*            idx = (int*)(ws + WS_IDX_OFF);
  unsigned short* U   = (unsigned short*)(ws + WS_U_OFF);

  int nq = in_sizes[2] / 1024;          // 16384
  int nwaves = nq / 16;                 // 1024
  int nblocks = (nwaves + 3) / 4;       // 256

  hipLaunchKernelGGL(dsn_gram,  dim3(69), dim3(256), 0, stream, support, labels, G);
  hipLaunchKernelGGL(dsn_eig,   dim3(1),  dim3(64),  0, stream, labels, G, W, idx);
  hipLaunchKernelGGL(dsn_basis, dim3(80), dim3(256), 0, stream, support, W, idx, U);
  hipLaunchKernelGGL(dsn_main,  dim3(nblocks), dim3(256), 0, stream, query, U, out);
}